// Round 1
// 144.448 us; speedup vs baseline: 1.0159x; 1.0159x over previous
//
#include <hip/hip_runtime.h>
#include <math.h>

#define ALPHA 8.3f
#define STAGE_BYTES 26112    // 1632 granules * 16 B (6 rows x 34 cols x 8 granules)

typedef short v8s  __attribute__((ext_vector_type(8)));
typedef float v16f __attribute__((ext_vector_type(16)));
typedef float v4f  __attribute__((ext_vector_type(4)));

static __device__ __forceinline__ unsigned short f2bf(float f) {
    unsigned int u = __float_as_uint(f);
    u = (u + 0x7fffu + ((u >> 16) & 1u)) >> 16;   // RNE
    return (unsigned short)u;
}

static __device__ __forceinline__ void async16(const void* g, void* l) {
    __builtin_amdgcn_global_load_lds(
        (const __attribute__((address_space(1))) unsigned int*)g,
        (__attribute__((address_space(3))) unsigned int*)l, 16, 0, 0);
}

// A-fragment pre-swizzle (verified R2-R4):
// wt[((tap*32 + ks)*2 + mt)*64 + lane][8] ; o = mt*32+(lane&31), c = ks*16+(lane>>5)*8+j
// Also zeroes the 1 KB halo buffer (block 0) -> hipMemsetAsync dispatch removed.
__global__ void prep_weights(const float* __restrict__ w, unsigned short* __restrict__ wt,
                             float* __restrict__ zb) {
    if (blockIdx.x == 0) zb[threadIdx.x] = 0.f;   // 256 floats = 1 KB
    int i = blockIdx.x * 256 + threadIdx.x;
    if (i >= 9 * 32 * 2 * 64 * 8) return;
    int j    = i & 7;
    int lane = (i >> 3) & 63;
    int mt   = (i >> 9) & 1;
    int ks   = (i >> 10) & 31;
    int tap  = i >> 15;
    int o = mt * 32 + (lane & 31);
    int c = ks * 16 + (lane >> 5) * 8 + j;
    wt[i] = f2bf(w[(o * 512 + c) * 9 + tap]);
}

// x fp32 NCHW -> bf16 NHWC (x2[b][h][w][c]).
// v6: float4 global loads (4x fewer load instrs), channel-halved blocks (grid 1024,
// 4 blocks/CU) for latency hiding. Values bit-identical to v5.
__global__ __launch_bounds__(256) void nhwc_cast(const float* __restrict__ x,
                                                 unsigned short* __restrict__ x2) {
    __shared__ float st[64][65];
    const int bx  = blockIdx.x;
    const int ch2 = bx & 1;           // channel half (256 ch)
    const int h   = (bx >> 1) & 63;
    const int b   = bx >> 7;
    const int tid = threadIdx.x;
    const float* xb = x + ((size_t)b * 512 + ch2 * 256) * 4096 + h * 64;
    unsigned short* ob = x2 + (((size_t)b * 64 + h) * 64) * 512 + ch2 * 256;
    for (int cb = 0; cb < 4; ++cb) {
        __syncthreads();
#pragma unroll
        for (int i = 0; i < 4; ++i) {
            const int c  = i * 16 + (tid >> 4);
            const int w4 = (tid & 15) * 4;
            const float4 v = *(const float4*)&xb[(size_t)(cb * 64 + c) * 4096 + w4];
            st[c][w4]     = v.x;      // stride-65 rows: 2-way bank alias (free)
            st[c][w4 + 1] = v.y;
            st[c][w4 + 2] = v.z;
            st[c][w4 + 3] = v.w;
        }
        __syncthreads();
#pragma unroll
        for (int j = 0; j < 2; ++j) {
            const int idx = j * 256 + tid;
            const int w = idx >> 3, k = idx & 7;
            unsigned short t[8];
#pragma unroll
            for (int e = 0; e < 8; ++e) t[e] = f2bf(st[k * 8 + e][w]);
            uint4 u;
            u.x = t[0] | ((unsigned)t[1] << 16);
            u.y = t[2] | ((unsigned)t[3] << 16);
            u.z = t[4] | ((unsigned)t[5] << 16);
            u.w = t[6] | ((unsigned)t[7] << 16);
            *(uint4*)&ob[(size_t)w * 512 + cb * 64 + k * 8] = u;
        }
    }
}

// Main v6: 256 blocks (1/CU) x 1024 thr = 16 waves/CU (was 8) -> 4 waves/SIMD.
// Waves = mt(2) x rt(4) x kh(2); each wave owns ONE output row (nt removed), 32 cols,
// M=32 (mt), K=256 (kh). Per-output accumulation order identical to v5 (bit-exact).
// 8 supersteps x 64 ch DMA-staged via global_load_lds, double-buffered.
__global__ __launch_bounds__(1024, 4)
void depthconv_v6(const unsigned short* __restrict__ x2,
                  const float* __restrict__ depth,
                  const unsigned short* __restrict__ wt,
                  const float* __restrict__ zbuf,
                  float* __restrict__ out) {
    __shared__ __align__(16) char smem[2 * STAGE_BYTES];   // 52,224 B (epilogue reuses)

    // XCD-swizzled decode: xcd owns rows [xcd*8, xcd*8+8) for all (b, wtile)
    const int bx   = blockIdx.x;
    const int xcd  = bx & 7;
    const int i0   = bx >> 3;          // 0..31
    const int wt2  = i0 & 1;
    const int b    = (i0 >> 1) & 7;
    const int ht   = xcd * 2 + (i0 >> 4);
    const int h0 = ht * 4, w0 = wt2 * 32;

    const int tid  = threadIdx.x;
    const int wid  = tid >> 6;         // 0..15
    const int lane = tid & 63;
    const int l31  = lane & 31;
    const int half = lane >> 5;
    const int mt   = wid & 1;
    const int rt   = (wid >> 1) & 3;   // wave's row within the 4-row tile
    const int kh   = wid >> 3;

    const char* xpix = (const char*)(x2 + ((size_t)b * 4096) * 512);

    // ---- gates for my single row (fp32, OOB depth = 0; verified R2) ----
    float gt[9];
    {
        const float* dp = depth + (size_t)b * 4096;
        const int hq = h0 + rt, wq = w0 + l31;
        const float d0 = dp[hq * 64 + wq];
#pragma unroll
        for (int t = 0; t < 9; ++t) {
            const int hn = hq + t / 3 - 1, wn = wq + t % 3 - 1;
            const float dn = (hn >= 0 && hn < 64 && wn >= 0 && wn < 64) ? dp[hn * 64 + wn] : 0.f;
            gt[t] = __expf(-ALPHA * fabsf(d0 - dn));
        }
    }

    v16f acc;
    v16f vzero;
#pragma unroll
    for (int r = 0; r < 16; ++r) { acc[r] = 0.f; vzero[r] = 0.f; }

    // granule i (0..1631): slice = i>>3 (r*34+c, rows h0-1..h0+4, cols w0-1..w0+32),
    // gg = (i&7)^(slice&7); content = ch [(gg>>2)*256 + ss*32 + (gg&3)*8, +8).
    // LDS lane-linear (DMA), reads land conflict-free via the i-space XOR.
#define ISSUE(SS)                                                               \
    {                                                                           \
        const int ss_ = (SS);                                                   \
        char* bufb = smem + (ss_ & 1) * STAGE_BYTES;                            \
        _Pragma("unroll")                                                       \
        for (int it = 0; it < 2; ++it) {                                        \
            const int i = it * 1024 + tid;                                      \
            if (i < 1632) {                                                     \
                const int slice = i >> 3;                                       \
                const int gg = (i & 7) ^ (slice & 7);                           \
                const int r = slice / 34;                                       \
                const int c = slice - r * 34;                                   \
                const int hh = h0 - 1 + r, ww = w0 - 1 + c;                     \
                const char* gp = (hh >= 0 && hh < 64 && ww >= 0 && ww < 64)     \
                    ? xpix + (size_t)(hh * 64 + ww) * 1024                      \
                           + (gg >> 2) * 512 + ss_ * 64 + (gg & 3) * 16        \
                    : (const char*)zbuf;                                        \
                async16(gp, bufb + (size_t)i * 16);                             \
            }                                                                   \
        }                                                                       \
    }

    ISSUE(0);

    const int g0 = kh * 4 + half;        // kk=0 granule
    const int g1 = g0 + 2;               // kk=1 granule

    for (int ss = 0; ss < 8; ++ss) {
        __syncthreads();                    // drains DMA(ss) (vmcnt0) + fences prev compute
        if (ss < 7) ISSUE(ss + 1);          // DMA(ss+1) flies under compute(ss)
        const char* bufb = smem + (ss & 1) * STAGE_BYTES;
        const int ks0 = kh * 16 + ss * 2;
#pragma unroll
        for (int tap = 0; tap < 9; ++tap) {
            const int di = tap / 3, dj = tap % 3;
            const v8s a0 = *(const v8s*)&wt[(((tap * 32 + ks0) * 2 + mt) * 64 + lane) * 8];
            const v8s a1 = *(const v8s*)&wt[(((tap * 32 + ks0 + 1) * 2 + mt) * 64 + lane) * 8];
            const int slice = (rt + di) * 34 + l31 + dj;
            const int s7 = slice & 7;
            const v8s b0 = *(const v8s*)(bufb + ((size_t)(slice * 8 + (g0 ^ s7))) * 16);
            const v8s b1 = *(const v8s*)(bufb + ((size_t)(slice * 8 + (g1 ^ s7))) * 16);
            v16f pass = __builtin_amdgcn_mfma_f32_32x32x16_bf16(a0, b0, vzero, 0, 0, 0);
            pass = __builtin_amdgcn_mfma_f32_32x32x16_bf16(a1, b1, pass, 0, 0, 0);
            const float gv = gt[tap];
#pragma unroll
            for (int r = 0; r < 16; ++r)
                acc[r] = fmaf(gv, pass[r], acc[r]);
        }
    }

    // ---- in-block kh reduction (LDS reuses stage buffers), out written once ----
    __syncthreads();
    float* red = (float*)smem;
    const int region = mt * 4 + rt;        // 0..7, 4 KB each (32 KB total)
    if (kh == 1) {
#pragma unroll
        for (int qd = 0; qd < 4; ++qd) {
            v4f v;
            v[0] = acc[qd * 4];     v[1] = acc[qd * 4 + 1];
            v[2] = acc[qd * 4 + 2]; v[3] = acc[qd * 4 + 3];
            *(v4f*)&red[region * 1024 + lane * 16 + qd * 4] = v;
        }
    }
    __syncthreads();
    if (kh == 0) {
        float* ob = out + ((size_t)b * 64) * 4096 + (h0 + rt) * 64 + w0;
#pragma unroll
        for (int qd = 0; qd < 4; ++qd) {
            const v4f v = *(const v4f*)&red[region * 1024 + lane * 16 + qd * 4];
#pragma unroll
            for (int j = 0; j < 4; ++j) {
                const int rg = qd * 4 + j;
                const int o = mt * 32 + (rg & 3) + 8 * (rg >> 2) + 4 * half;  // verified C-layout
                ob[(size_t)o * 4096 + l31] = acc[rg] + v[j];
            }
        }
    }
}

extern "C" void kernel_launch(void* const* d_in, const int* in_sizes, int n_in,
                              void* d_out, int out_size, void* d_ws, size_t ws_size,
                              hipStream_t stream) {
    const float* x      = (const float*)d_in[0];
    const float* depth  = (const float*)d_in[1];
    const float* weight = (const float*)d_in[2];
    float* out = (float*)d_out;

    unsigned short* wtb = (unsigned short*)d_ws;                        // 589,824 B
    float* zbuf         = (float*)((char*)d_ws + 786432);               // 1 KB zeros (halo)
    unsigned short* x2  = (unsigned short*)((char*)d_ws + (1 << 20));   // 33.6 MB bf16 NHWC

    prep_weights<<<1152, 256, 0, stream>>>(weight, wtb, zbuf);   // also zeroes zbuf
    nhwc_cast<<<1024, 256, 0, stream>>>(x, x2);
    depthconv_v6<<<256, 1024, 0, stream>>>(x2, depth, wtb, zbuf, out);
}

// Round 2
// 141.712 us; speedup vs baseline: 1.0355x; 1.0193x over previous
//
#include <hip/hip_runtime.h>
#include <math.h>

#define ALPHA 8.3f
#define STAGE_BYTES 17408    // 1088 granules * 16 B (4 rows x 34 cols x 8 granules)

typedef short v8s  __attribute__((ext_vector_type(8)));
typedef float v16f __attribute__((ext_vector_type(16)));
typedef float v4f  __attribute__((ext_vector_type(4)));

static __device__ __forceinline__ unsigned short f2bf(float f) {
    unsigned int u = __float_as_uint(f);
    u = (u + 0x7fffu + ((u >> 16) & 1u)) >> 16;   // RNE
    return (unsigned short)u;
}

static __device__ __forceinline__ void async16(const void* g, void* l) {
    __builtin_amdgcn_global_load_lds(
        (const __attribute__((address_space(1))) unsigned int*)g,
        (__attribute__((address_space(3))) unsigned int*)l, 16, 0, 0);
}

// A-fragment pre-swizzle (verified R2-R4):
// wt[((tap*32 + ks)*2 + mt)*64 + lane][8] ; o = mt*32+(lane&31), c = ks*16+(lane>>5)*8+j
// Also zeroes the 1 KB halo buffer (block 0) -> no hipMemsetAsync dispatch.
__global__ void prep_weights(const float* __restrict__ w, unsigned short* __restrict__ wt,
                             float* __restrict__ zb) {
    if (blockIdx.x == 0) zb[threadIdx.x] = 0.f;   // 256 floats = 1 KB
    int i = blockIdx.x * 256 + threadIdx.x;
    if (i >= 9 * 32 * 2 * 64 * 8) return;
    int j    = i & 7;
    int lane = (i >> 3) & 63;
    int mt   = (i >> 9) & 1;
    int ks   = (i >> 10) & 31;
    int tap  = i >> 15;
    int o = mt * 32 + (lane & 31);
    int c = ks * 16 + (lane >> 5) * 8 + j;
    wt[i] = f2bf(w[(o * 512 + c) * 9 + tap]);
}

// x fp32 NCHW -> bf16 NHWC (x2[b][h][w][c]).
// float4 global loads, channel-halved blocks (grid 1024, 4 blocks/CU). Bit-identical values.
__global__ __launch_bounds__(256) void nhwc_cast(const float* __restrict__ x,
                                                 unsigned short* __restrict__ x2) {
    __shared__ float st[64][65];
    const int bx  = blockIdx.x;
    const int ch2 = bx & 1;           // channel half (256 ch)
    const int h   = (bx >> 1) & 63;
    const int b   = bx >> 7;
    const int tid = threadIdx.x;
    const float* xb = x + ((size_t)b * 512 + ch2 * 256) * 4096 + h * 64;
    unsigned short* ob = x2 + (((size_t)b * 64 + h) * 64) * 512 + ch2 * 256;
    for (int cb = 0; cb < 4; ++cb) {
        __syncthreads();
#pragma unroll
        for (int i = 0; i < 4; ++i) {
            const int c  = i * 16 + (tid >> 4);
            const int w4 = (tid & 15) * 4;
            const float4 v = *(const float4*)&xb[(size_t)(cb * 64 + c) * 4096 + w4];
            st[c][w4]     = v.x;
            st[c][w4 + 1] = v.y;
            st[c][w4 + 2] = v.z;
            st[c][w4 + 3] = v.w;
        }
        __syncthreads();
#pragma unroll
        for (int j = 0; j < 2; ++j) {
            const int idx = j * 256 + tid;
            const int w = idx >> 3, k = idx & 7;
            unsigned short t[8];
#pragma unroll
            for (int e = 0; e < 8; ++e) t[e] = f2bf(st[k * 8 + e][w]);
            uint4 u;
            u.x = t[0] | ((unsigned)t[1] << 16);
            u.y = t[2] | ((unsigned)t[3] << 16);
            u.z = t[4] | ((unsigned)t[5] << 16);
            u.w = t[6] | ((unsigned)t[7] << 16);
            *(uint4*)&ob[(size_t)w * 512 + cb * 64 + k * 8] = u;
        }
    }
}

// Main v7: 512 blocks x 512 thr -> 2 INDEPENDENT blocks/CU (v5/v6 had 1 lockstep
// block/CU; barrier+vmcnt drains idled the whole CU 8x per block -> 80% stall,
// insensitive to waves-per-block). Block = (b, 2 rows, 32 cols), full K.
// 8 waves = mt(2) x rt(2) x kh(2); each wave owns ONE row, M=32, K=256.
// Per-output accumulation order identical to v5/v6 (bit-exact).
__global__ __launch_bounds__(512, 4)
void depthconv_v7(const unsigned short* __restrict__ x2,
                  const float* __restrict__ depth,
                  const unsigned short* __restrict__ wt,
                  const float* __restrict__ zbuf,
                  float* __restrict__ out) {
    __shared__ __align__(16) char smem[2 * STAGE_BYTES];   // 34,816 B (epilogue reuses)

    // XCD-swizzled decode: xcd owns rows [xcd*8, xcd*8+8) for all (b, wtile)
    const int bx   = blockIdx.x;
    const int xcd  = bx & 7;
    const int i0   = bx >> 3;          // 0..63
    const int wt2  = i0 & 1;
    const int b    = (i0 >> 1) & 7;
    const int ht   = xcd * 4 + (i0 >> 4);   // 0..31 row-tiles (2 rows each)
    const int h0 = ht * 2, w0 = wt2 * 32;

    const int tid  = threadIdx.x;
    const int wid  = tid >> 6;         // 0..7
    const int lane = tid & 63;
    const int l31  = lane & 31;
    const int half = lane >> 5;
    const int mt   = wid & 1;
    const int rt   = (wid >> 1) & 1;   // wave's row within the 2-row tile
    const int kh   = wid >> 2;

    const char* xpix = (const char*)(x2 + ((size_t)b * 4096) * 512);

    // ---- gates for my single row (fp32, OOB depth = 0; verified R2) ----
    float gt[9];
    {
        const float* dp = depth + (size_t)b * 4096;
        const int hq = h0 + rt, wq = w0 + l31;
        const float d0 = dp[hq * 64 + wq];
#pragma unroll
        for (int t = 0; t < 9; ++t) {
            const int hn = hq + t / 3 - 1, wn = wq + t % 3 - 1;
            const float dn = (hn >= 0 && hn < 64 && wn >= 0 && wn < 64) ? dp[hn * 64 + wn] : 0.f;
            gt[t] = __expf(-ALPHA * fabsf(d0 - dn));
        }
    }

    v16f acc;
    v16f vzero;
#pragma unroll
    for (int r = 0; r < 16; ++r) { acc[r] = 0.f; vzero[r] = 0.f; }

    // granule i (0..1087): slice = i>>3 (r*34+c, rows h0-1..h0+2, cols w0-1..w0+32),
    // gg = (i&7)^(slice&7); content = ch [(gg>>2)*256 + ss*32 + (gg&3)*8, +8).
    // LDS lane-linear (DMA), reads land conflict-free via the i-space XOR.
#define ISSUE(SS)                                                               \
    {                                                                           \
        const int ss_ = (SS);                                                   \
        char* bufb = smem + (ss_ & 1) * STAGE_BYTES;                            \
        _Pragma("unroll")                                                       \
        for (int it = 0; it < 3; ++it) {                                        \
            const int i = it * 512 + tid;                                       \
            if (i < 1088) {                                                     \
                const int slice = i >> 3;                                       \
                const int gg = (i & 7) ^ (slice & 7);                           \
                const int r = slice / 34;                                       \
                const int c = slice - r * 34;                                   \
                const int hh = h0 - 1 + r, ww = w0 - 1 + c;                     \
                const char* gp = (hh >= 0 && hh < 64 && ww >= 0 && ww < 64)     \
                    ? xpix + (size_t)(hh * 64 + ww) * 1024                      \
                           + (gg >> 2) * 512 + ss_ * 64 + (gg & 3) * 16        \
                    : (const char*)zbuf;                                        \
                async16(gp, bufb + (size_t)i * 16);                             \
            }                                                                   \
        }                                                                       \
    }

    ISSUE(0);

    const int g0 = kh * 4 + half;        // kk=0 granule
    const int g1 = g0 + 2;               // kk=1 granule

    for (int ss = 0; ss < 8; ++ss) {
        __syncthreads();                    // drains DMA(ss) (vmcnt0) + fences prev compute
        if (ss < 7) ISSUE(ss + 1);          // DMA(ss+1) flies under compute(ss)
        const char* bufb = smem + (ss & 1) * STAGE_BYTES;
        const int ks0 = kh * 16 + ss * 2;
#pragma unroll
        for (int tap = 0; tap < 9; ++tap) {
            const int di = tap / 3, dj = tap % 3;
            const v8s a0 = *(const v8s*)&wt[(((tap * 32 + ks0) * 2 + mt) * 64 + lane) * 8];
            const v8s a1 = *(const v8s*)&wt[(((tap * 32 + ks0 + 1) * 2 + mt) * 64 + lane) * 8];
            const int slice = (rt + di) * 34 + l31 + dj;
            const int s7 = slice & 7;
            const v8s b0 = *(const v8s*)(bufb + ((size_t)(slice * 8 + (g0 ^ s7))) * 16);
            const v8s b1 = *(const v8s*)(bufb + ((size_t)(slice * 8 + (g1 ^ s7))) * 16);
            v16f pass = __builtin_amdgcn_mfma_f32_32x32x16_bf16(a0, b0, vzero, 0, 0, 0);
            pass = __builtin_amdgcn_mfma_f32_32x32x16_bf16(a1, b1, pass, 0, 0, 0);
            const float gv = gt[tap];
#pragma unroll
            for (int r = 0; r < 16; ++r)
                acc[r] = fmaf(gv, pass[r], acc[r]);
        }
    }

    // ---- in-block kh reduction (LDS reuses stage buffers), out written once ----
    __syncthreads();
    float* red = (float*)smem;
    const int region = mt * 2 + rt;        // 0..3, 4 KB each (16 KB of 34.8 KB)
    if (kh == 1) {
#pragma unroll
        for (int qd = 0; qd < 4; ++qd) {
            v4f v;
            v[0] = acc[qd * 4];     v[1] = acc[qd * 4 + 1];
            v[2] = acc[qd * 4 + 2]; v[3] = acc[qd * 4 + 3];
            *(v4f*)&red[region * 1024 + lane * 16 + qd * 4] = v;
        }
    }
    __syncthreads();
    if (kh == 0) {
        float* ob = out + ((size_t)b * 64) * 4096 + (h0 + rt) * 64 + w0;
#pragma unroll
        for (int qd = 0; qd < 4; ++qd) {
            const v4f v = *(const v4f*)&red[region * 1024 + lane * 16 + qd * 4];
#pragma unroll
            for (int j = 0; j < 4; ++j) {
                const int rg = qd * 4 + j;
                const int o = mt * 32 + (rg & 3) + 8 * (rg >> 2) + 4 * half;  // verified C-layout
                ob[(size_t)o * 4096 + l31] = acc[rg] + v[j];
            }
        }
    }
}

extern "C" void kernel_launch(void* const* d_in, const int* in_sizes, int n_in,
                              void* d_out, int out_size, void* d_ws, size_t ws_size,
                              hipStream_t stream) {
    const float* x      = (const float*)d_in[0];
    const float* depth  = (const float*)d_in[1];
    const float* weight = (const float*)d_in[2];
    float* out = (float*)d_out;

    unsigned short* wtb = (unsigned short*)d_ws;                        // 589,824 B
    float* zbuf         = (float*)((char*)d_ws + 786432);               // 1 KB zeros (halo)
    unsigned short* x2  = (unsigned short*)((char*)d_ws + (1 << 20));   // 33.6 MB bf16 NHWC

    prep_weights<<<1152, 256, 0, stream>>>(weight, wtb, zbuf);   // also zeroes zbuf
    nhwc_cast<<<1024, 256, 0, stream>>>(x, x2);
    depthconv_v7<<<512, 512, 0, stream>>>(x2, depth, wtb, zbuf, out);
}